// Round 3
// baseline (332.576 us; speedup 1.0000x reference)
//
#include <hip/hip_runtime.h>

typedef unsigned short u16;
typedef unsigned int u32;
typedef __attribute__((ext_vector_type(4))) float f32x4;
typedef __attribute__((ext_vector_type(4))) int i32x4;
typedef __attribute__((ext_vector_type(8))) int i32x8;
typedef __attribute__((ext_vector_type(4))) float f32x4v;

#define LSEQ 128
#define KW 8
#define NP 2104
#define MTOT 33664   // BATCH*NP = 263*128
#define FDIM 1088    // PAIR_FEAT
#define KPAD 1152    // padded feature dim = 9*128
#define GPAD 1152    // padded g dim = 9*128
#define W1SCALE 64.0f
#define W1INV 0.015625f

// ---- workspace layout (bytes) ----
#define WS_W1P  0ul          // fp8 [1152][1152] = 1,327,104
#define WS_EMOB 1327104ul    // fp8 [16*128][512] = 1,048,576
#define WS_CAUB 2375680ul    // fp8 [16*128][512] = 1,048,576
#define WS_SMB  3424256ul    // fp8 [17][128] = 2,176
#define WS_B1P  3426432ul    // f32 [1152]
#define WS_W2P  3431040ul    // f32 [1152]
#define WS_TABI 3435648ul    // int [2104]
#define WS_TABJ 3444064ul    // int [2104]
#define WS_TABR 3452480ul    // int [2104] (end 3,460,896)

__device__ __forceinline__ void load_lds16(const void* g, void* l) {
  __builtin_amdgcn_global_load_lds(
      (const __attribute__((address_space(1))) void*)g,
      (__attribute__((address_space(3))) void*)l, 16, 0, 0);
}

__device__ __forceinline__ int pack4_fp8(float a, float b, float c, float d) {
  int p = 0;
  p = __builtin_amdgcn_cvt_pk_fp8_f32(a, b, p, false);
  p = __builtin_amdgcn_cvt_pk_fp8_f32(c, d, p, true);
  return p;
}

// ---- fused setup ----
// blockIdx.x [0,1296):    W1 -> fp8*64, padded [1152][1152]
//            [1296,3378): H_emo/H_cause -> fp8 ; pred init = b2
//            3378:        tables, sm17 fp8, b1p/w2p, emo_cau_pos
__global__ void setup_all(const float* __restrict__ emo, const float* __restrict__ cau,
                          const float* __restrict__ pos_emb, const float* __restrict__ W1,
                          const float* __restrict__ b1, const float* __restrict__ W2,
                          const float* __restrict__ b2,
                          char* __restrict__ W1p, char* __restrict__ emoB,
                          char* __restrict__ cauB, char* __restrict__ smB,
                          float* __restrict__ b1p, float* __restrict__ w2p,
                          int* __restrict__ tab_i, int* __restrict__ tab_j,
                          int* __restrict__ tab_r,
                          float* __restrict__ pred, float* __restrict__ out_pos) {
  const int bx = blockIdx.x;
  const int t = threadIdx.x;
  if (bx < 1296) {
    int idx = bx * 256 + t;           // int-units: 1152*288 = 331776
    if (idx >= 331776) return;
    int g = idx / 288;
    int f4 = idx - g * 288;
    int f = f4 * 4;
    int pack = 0;
    if (g < 1088 && f < 1088) {
      f32x4v v = *(const f32x4v*)&W1[g * 1088 + f];
      pack = pack4_fp8(v.x * W1SCALE, v.y * W1SCALE, v.z * W1SCALE, v.w * W1SCALE);
    }
    ((int*)W1p)[g * 288 + f4] = pack;
  } else if (bx < 3378) {
    int idx = (bx - 1296) * 256 + t;  // 4-float units
    if (idx < 262144) {
      f32x4v v = *(const f32x4v*)&emo[idx * 4];
      ((int*)emoB)[idx] = pack4_fp8(v.x, v.y, v.z, v.w);
    } else if (idx < 524288) {
      int k = idx - 262144;
      f32x4v v = *(const f32x4v*)&cau[k * 4];
      ((int*)cauB)[k] = pack4_fp8(v.x, v.y, v.z, v.w);
    } else {
      int k = idx - 524288;           // 8416 vec4 units cover 33664 floats
      if (k < 8416) {
        float bv = b2[0];
        f32x4v o = {bv, bv, bv, bv};
        *(f32x4v*)&pred[k * 4] = o;
      }
    }
  } else {
    if (t < LSEQ) {
      int i = t;
      int off = 0;
      for (int tt = 0; tt < i; ++tt) {
        int lo = tt - KW; if (lo < 0) lo = 0;
        int hi = tt + KW; if (hi > LSEQ - 1) hi = LSEQ - 1;
        off += hi - lo + 1;
      }
      int jlo = i - KW; if (jlo < 0) jlo = 0;
      int jhi = i + KW; if (jhi > LSEQ - 1) jhi = LSEQ - 1;
      for (int j = jlo; j <= jhi; ++j) {
        int p = off + (j - jlo);
        tab_i[p] = i; tab_j[p] = j; tab_r[p] = j - i;
        out_pos[2 * p]     = (float)(i + 1);
        out_pos[2 * p + 1] = (float)(j + 1);
      }
    }
    // sm17[r][d] = sum_s (128-|s-8|)*exp(-(r-s)^2)*pos_emb[s][d]; cols 64..127 = 0
    for (int u = t; u < 17 * 32; u += 256) {   // int-units of [17][128]
      int r = u >> 5, c4 = u & 31;
      float vals[4];
      for (int x = 0; x < 4; ++x) {
        int d = c4 * 4 + x;
        float acc = 0.f;
        if (d < 64) {
          for (int s = 0; s < 17; ++s) {
            float diff = (float)(r - s);
            int a = s - 8; if (a < 0) a = -a;
            acc += (float)(128 - a) * expf(-diff * diff) * pos_emb[s * 64 + d];
          }
        }
        vals[x] = acc;
      }
      ((int*)smB)[u] = pack4_fp8(vals[0], vals[1], vals[2], vals[3]);
    }
    for (int g = t; g < GPAD; g += 256) {
      b1p[g] = (g < FDIM) ? b1[g] : 0.f;
      w2p[g] = (g < FDIM) ? W2[g] : 0.f;
    }
  }
}

// ---- fused MX-fp8 GEMM: pred[r] += sum_g relu(couples·W1[g]+b1[g]) * W2[g] ----
// 128x128 tile, BK=128, mfma_scale 16x16x128 f8f6f4 (fp8/fp8, neutral scales)
__global__ __launch_bounds__(256, 2)
void pair_gemm(const char* __restrict__ emoB, const char* __restrict__ cauB,
               const char* __restrict__ smB, const char* __restrict__ W1p,
               const float* __restrict__ b1p, const float* __restrict__ w2p,
               const int* __restrict__ tab_i, const int* __restrict__ tab_j,
               const int* __restrict__ tab_r,
               float* __restrict__ pred) {
  __shared__ __align__(16) char As[128 * 128];
  __shared__ __align__(16) char Bs[128 * 128];
  __shared__ u32 offE[128], offC[128], offS[128];
  __shared__ float predAcc[2][128];

  const int tid = threadIdx.x;

  if (tid < 128) {
    int r = blockIdx.x * 128 + tid;
    int b = r / NP;
    int p = r - b * NP;
    offE[tid] = (u32)((b * LSEQ + tab_i[p]) * 512);
    offC[tid] = (u32)((b * LSEQ + tab_j[p]) * 512);
    offS[tid] = (u32)((tab_r[p] + KW) * 128);
    predAcc[0][tid] = 0.f;
    predAcc[1][tid] = 0.f;
  }
  __syncthreads();

  const int lane = tid & 63;
  const int w = tid >> 6;
  const int lrow = lane & 15;
  const int q2 = lane >> 4;
  const int wm = (w >> 1) * 64;
  const int wn = (w & 1) * 64;
  // swizzled 16B-chunk offsets for the two halves of the 32B K-fragment
  const int ca0 = (((q2 << 1) ^ (lrow & 7)) << 4);
  const int ca1 = ((((q2 << 1) | 1) ^ (lrow & 7)) << 4);

  // staging mapping: thread covers (row = q*32 + (tid>>3), chunk = tid&7),
  // source chunk XOR-swizzled by row so LDS dest stays lane*16-contiguous
  const int trow = tid >> 3;
  const int csw = (((tid & 7) ^ (trow & 7)) << 4);
  const int gbase = blockIdx.y * 128;

  u32 aE[4], aC[4], aS[4];
  const char* bB[4];
  char* ldsA[4];
  char* ldsB[4];
#pragma unroll
  for (int q = 0; q < 4; ++q) {
    int row = q * 32 + trow;
    aE[q] = offE[row] + csw;
    aC[q] = offC[row] + csw;
    aS[q] = offS[row] + csw;
    bB[q] = W1p + (size_t)(gbase + row) * KPAD + csw;
    ldsA[q] = As + q * 4096 + w * 1024;
    ldsB[q] = Bs + q * 4096 + w * 1024;
  }

  f32x4 acc[4][4];
#pragma unroll
  for (int mi = 0; mi < 4; ++mi)
#pragma unroll
    for (int ni = 0; ni < 4; ++ni) acc[mi][ni] = (f32x4){0.f, 0.f, 0.f, 0.f};

  for (int ks = 0; ks < 9; ++ks) {
    const int f0 = ks << 7;
#pragma unroll
    for (int q = 0; q < 4; ++q) {
      const char* ap;
      if (ks < 4)       ap = emoB + aE[q] + f0;
      else if (ks < 8)  ap = cauB + aC[q] + (f0 - 512);
      else              ap = smB + aS[q];
      load_lds16(ap, ldsA[q]);
      load_lds16(bB[q] + f0, ldsB[q]);
    }
    __syncthreads();

    i32x8 bv[4];
#pragma unroll
    for (int ni = 0; ni < 4; ++ni) {
      const char* base = Bs + (wn + ni * 16 + lrow) * 128;
      i32x4 lo = *(const i32x4*)(base + ca0);
      i32x4 hi = *(const i32x4*)(base + ca1);
      bv[ni] = __builtin_shufflevector(lo, hi, 0, 1, 2, 3, 4, 5, 6, 7);
    }
#pragma unroll
    for (int mi = 0; mi < 4; ++mi) {
      const char* base = As + (wm + mi * 16 + lrow) * 128;
      i32x4 lo = *(const i32x4*)(base + ca0);
      i32x4 hi = *(const i32x4*)(base + ca1);
      i32x8 av = __builtin_shufflevector(lo, hi, 0, 1, 2, 3, 4, 5, 6, 7);
#pragma unroll
      for (int ni = 0; ni < 4; ++ni)
        acc[mi][ni] = __builtin_amdgcn_mfma_scale_f32_16x16x128_f8f6f4(
            av, bv[ni], acc[mi][ni], 0, 0, 0, 0x7f7f7f7f, 0, 0x7f7f7f7f);
    }
    __syncthreads();
  }

  // epilogue: un-scale W1 (x1/64), +b1, relu, dot W2, reduce over g-cols
  float rs[4][4];
#pragma unroll
  for (int mi = 0; mi < 4; ++mi)
#pragma unroll
    for (int r2 = 0; r2 < 4; ++r2) rs[mi][r2] = 0.f;

#pragma unroll
  for (int ni = 0; ni < 4; ++ni) {
    int g = gbase + wn + ni * 16 + lrow;
    float w2v = w2p[g];
    float b1v = b1p[g];
#pragma unroll
    for (int mi = 0; mi < 4; ++mi)
#pragma unroll
      for (int r2 = 0; r2 < 4; ++r2) {
        float hv = acc[mi][ni][r2] * W1INV + b1v;
        hv = fmaxf(hv, 0.f);
        rs[mi][r2] += hv * w2v;
      }
  }
#pragma unroll
  for (int mi = 0; mi < 4; ++mi)
#pragma unroll
    for (int r2 = 0; r2 < 4; ++r2) {
      float v2 = rs[mi][r2];
      v2 += __shfl_xor(v2, 1, 16);
      v2 += __shfl_xor(v2, 2, 16);
      v2 += __shfl_xor(v2, 4, 16);
      v2 += __shfl_xor(v2, 8, 16);
      if (lrow == 0)
        predAcc[w & 1][wm + mi * 16 + q2 * 4 + r2] += v2;
    }
  __syncthreads();
  if (tid < 128) {
    int r = blockIdx.x * 128 + tid;
    atomicAdd(&pred[r], predAcc[0][tid] + predAcc[1][tid]);
  }
}

extern "C" void kernel_launch(void* const* d_in, const int* in_sizes, int n_in,
                              void* d_out, int out_size, void* d_ws, size_t ws_size,
                              hipStream_t stream) {
  const float* h_emo = (const float*)d_in[0];
  const float* h_cau = (const float*)d_in[1];
  const float* pos_emb = (const float*)d_in[2];
  const float* W1 = (const float*)d_in[3];
  const float* b1 = (const float*)d_in[4];
  const float* W2 = (const float*)d_in[5];
  const float* b2 = (const float*)d_in[6];

  char* ws = (char*)d_ws;
  char* W1p = ws + WS_W1P;
  char* emoB = ws + WS_EMOB;
  char* cauB = ws + WS_CAUB;
  char* smB = ws + WS_SMB;
  float* b1p = (float*)(ws + WS_B1P);
  float* w2p = (float*)(ws + WS_W2P);
  int* tab_i = (int*)(ws + WS_TABI);
  int* tab_j = (int*)(ws + WS_TABJ);
  int* tab_r = (int*)(ws + WS_TABR);

  float* pred = (float*)d_out;
  float* out_pos = (float*)d_out + MTOT;

  setup_all<<<3379, 256, 0, stream>>>(h_emo, h_cau, pos_emb, W1, b1, W2, b2,
                                      W1p, emoB, cauB, smB, b1p, w2p,
                                      tab_i, tab_j, tab_r, pred, out_pos);
  pair_gemm<<<dim3(263, 9), 256, 0, stream>>>(emoB, cauB, smB, W1p, b1p, w2p,
                                              tab_i, tab_j, tab_r, pred);
}

// Round 5
// 205.193 us; speedup vs baseline: 1.6208x; 1.6208x over previous
//
#include <hip/hip_runtime.h>

typedef unsigned short u16;
typedef unsigned int u32;
typedef __attribute__((ext_vector_type(4))) float f32x4;
typedef __attribute__((ext_vector_type(4))) int i32x4;
typedef __attribute__((ext_vector_type(8))) int i32x8;
typedef __attribute__((ext_vector_type(4))) float f32x4v;

#define LSEQ 128
#define KW 8
#define NP 2104
#define MTOT 33664   // BATCH*NP = 263*128
#define FDIM 1088    // PAIR_FEAT
#define KPAD 1152    // padded feature dim = 9*128
#define GPAD 1152    // padded g dim = 9*128
#define W1SCALE 64.0f
#define W1INV 0.015625f

// ---- workspace layout (bytes) ----
#define WS_W1P  0ul          // fp8 [1152][1152] = 1,327,104
#define WS_EMOB 1327104ul    // fp8 [16*128][512] = 1,048,576
#define WS_CAUB 2375680ul    // fp8 [16*128][512] = 1,048,576
#define WS_SMB  3424256ul    // fp8 [17][128] = 2,176
#define WS_B1P  3426432ul    // f32 [1152]
#define WS_W2P  3431040ul    // f32 [1152]
#define WS_TABI 3435648ul    // int [2104]
#define WS_TABJ 3444064ul    // int [2104]
#define WS_TABR 3452480ul    // int [2104] (end 3,460,896)

__device__ __forceinline__ void load_lds16(const void* g, void* l) {
  __builtin_amdgcn_global_load_lds(
      (const __attribute__((address_space(1))) void*)g,
      (__attribute__((address_space(3))) void*)l, 16, 0, 0);
}

__device__ __forceinline__ int pack4_fp8(float a, float b, float c, float d) {
  int p = 0;
  p = __builtin_amdgcn_cvt_pk_fp8_f32(a, b, p, false);
  p = __builtin_amdgcn_cvt_pk_fp8_f32(c, d, p, true);
  return p;
}

// ---- fused setup ----
// blockIdx.x [0,1296):    W1 -> fp8*64, padded [1152][1152]
//            [1296,3378): H_emo/H_cause -> fp8 ; pred init = b2
//            3378:        tables, sm17 fp8, b1p/w2p, emo_cau_pos
__global__ void setup_all(const float* __restrict__ emo, const float* __restrict__ cau,
                          const float* __restrict__ pos_emb, const float* __restrict__ W1,
                          const float* __restrict__ b1, const float* __restrict__ W2,
                          const float* __restrict__ b2,
                          char* __restrict__ W1p, char* __restrict__ emoB,
                          char* __restrict__ cauB, char* __restrict__ smB,
                          float* __restrict__ b1p, float* __restrict__ w2p,
                          int* __restrict__ tab_i, int* __restrict__ tab_j,
                          int* __restrict__ tab_r,
                          float* __restrict__ pred, float* __restrict__ out_pos) {
  const int bx = blockIdx.x;
  const int t = threadIdx.x;
  if (bx < 1296) {
    int idx = bx * 256 + t;           // int-units: 1152*288 = 331776
    if (idx >= 331776) return;
    int g = idx / 288;
    int f4 = idx - g * 288;
    int f = f4 * 4;
    int pack = 0;
    if (g < 1088 && f < 1088) {
      f32x4v v = *(const f32x4v*)&W1[g * 1088 + f];
      pack = pack4_fp8(v.x * W1SCALE, v.y * W1SCALE, v.z * W1SCALE, v.w * W1SCALE);
    }
    ((int*)W1p)[g * 288 + f4] = pack;
  } else if (bx < 3378) {
    int idx = (bx - 1296) * 256 + t;  // 4-float units
    if (idx < 262144) {
      f32x4v v = *(const f32x4v*)&emo[idx * 4];
      ((int*)emoB)[idx] = pack4_fp8(v.x, v.y, v.z, v.w);
    } else if (idx < 524288) {
      int k = idx - 262144;
      f32x4v v = *(const f32x4v*)&cau[k * 4];
      ((int*)cauB)[k] = pack4_fp8(v.x, v.y, v.z, v.w);
    } else {
      int k = idx - 524288;           // 8416 vec4 units cover 33664 floats
      if (k < 8416) {
        float bv = b2[0];
        f32x4v o = {bv, bv, bv, bv};
        *(f32x4v*)&pred[k * 4] = o;
      }
    }
  } else {
    if (t < LSEQ) {
      int i = t;
      int off = 0;
      for (int tt = 0; tt < i; ++tt) {
        int lo = tt - KW; if (lo < 0) lo = 0;
        int hi = tt + KW; if (hi > LSEQ - 1) hi = LSEQ - 1;
        off += hi - lo + 1;
      }
      int jlo = i - KW; if (jlo < 0) jlo = 0;
      int jhi = i + KW; if (jhi > LSEQ - 1) jhi = LSEQ - 1;
      for (int j = jlo; j <= jhi; ++j) {
        int p = off + (j - jlo);
        tab_i[p] = i; tab_j[p] = j; tab_r[p] = j - i;
        out_pos[2 * p]     = (float)(i + 1);
        out_pos[2 * p + 1] = (float)(j + 1);
      }
    }
    // sm17[r][d] = sum_s (128-|s-8|)*exp(-(r-s)^2)*pos_emb[s][d]; cols 64..127 = 0
    for (int u = t; u < 17 * 32; u += 256) {   // int-units of [17][128]
      int r = u >> 5, c4 = u & 31;
      float vals[4];
      for (int x = 0; x < 4; ++x) {
        int d = c4 * 4 + x;
        float acc = 0.f;
        if (d < 64) {
          for (int s = 0; s < 17; ++s) {
            float diff = (float)(r - s);
            int a = s - 8; if (a < 0) a = -a;
            acc += (float)(128 - a) * expf(-diff * diff) * pos_emb[s * 64 + d];
          }
        }
        vals[x] = acc;
      }
      ((int*)smB)[u] = pack4_fp8(vals[0], vals[1], vals[2], vals[3]);
    }
    for (int g = t; g < GPAD; g += 256) {
      b1p[g] = (g < FDIM) ? b1[g] : 0.f;
      w2p[g] = (g < FDIM) ? W2[g] : 0.f;
    }
  }
}

// ---- fused MX-fp8 GEMM: pred[r] += sum_g relu(couples·W1[g]+b1[g]) * W2[g] ----
// 128x128 tile, BK=128, mfma_scale 16x16x128 f8f6f4 (fp8/fp8, neutral scales)
// launch_bounds(256,1): allocator free to use ~200 VGPRs (R3's (256,2) capped
// at 128 and spilled -> 612 MB scratch). A/B tiles in ONE shared array so the
// staging base "tiles+16384" provably aliases the B-tile (R4 bug: As+16384
// need not equal Bs under the backend's LDS layout policy).
__global__ __launch_bounds__(256, 1)
void pair_gemm(const char* __restrict__ emoB, const char* __restrict__ cauB,
               const char* __restrict__ smB, const char* __restrict__ W1p,
               const float* __restrict__ b1p, const float* __restrict__ w2p,
               const int* __restrict__ tab_i, const int* __restrict__ tab_j,
               const int* __restrict__ tab_r,
               float* __restrict__ pred) {
  __shared__ __align__(16) char tiles[32768];   // [0,16384)=A, [16384,32768)=B
  __shared__ u32 offE[128], offC[128], offS[128];
  __shared__ float predAcc[2][128];
  char* As = tiles;
  char* Bs = tiles + 16384;

  const int tid = threadIdx.x;

  if (tid < 128) {
    int r = blockIdx.x * 128 + tid;
    int b = r / NP;
    int p = r - b * NP;
    offE[tid] = (u32)((b * LSEQ + tab_i[p]) * 512);
    offC[tid] = (u32)((b * LSEQ + tab_j[p]) * 512);
    offS[tid] = (u32)((tab_r[p] + KW) * 128);
    predAcc[0][tid] = 0.f;
    predAcc[1][tid] = 0.f;
  }
  __syncthreads();

  const int lane = tid & 63;
  const int w = tid >> 6;
  const int lrow = lane & 15;
  const int q2 = lane >> 4;
  const int wm = (w >> 1) * 64;
  const int wn = (w & 1) * 64;
  // swizzled 16B-chunk offsets for the two halves of the 32B K-fragment
  const int ca0 = (((q2 << 1) ^ (lrow & 7)) << 4);
  const int ca1 = ((((q2 << 1) | 1) ^ (lrow & 7)) << 4);

  // staging mapping: thread covers (row = q*32 + (tid>>3), chunk = tid&7),
  // source chunk XOR-swizzled by row so LDS dest stays lane*16-contiguous
  const int trow = tid >> 3;
  const int csw = (((tid & 7) ^ (trow & 7)) << 4);
  const int gbase = blockIdx.y * 128;

  u32 aE[4], aC[4], aS[4];
#pragma unroll
  for (int q = 0; q < 4; ++q) {
    int row = q * 32 + trow;
    aE[q] = offE[row] + csw;
    aC[q] = offC[row] + csw;
    aS[q] = offS[row] + csw;
  }
  const char* bBase = W1p + (size_t)(gbase + trow) * KPAD + csw;
  char* ldsBase = tiles + w * 1024;   // A dest; B dest = +16384

  f32x4 acc[4][4];
#pragma unroll
  for (int mi = 0; mi < 4; ++mi)
#pragma unroll
    for (int ni = 0; ni < 4; ++ni) acc[mi][ni] = (f32x4){0.f, 0.f, 0.f, 0.f};

  for (int ks = 0; ks < 9; ++ks) {
    const int f0 = ks << 7;
#pragma unroll
    for (int q = 0; q < 4; ++q) {
      const char* ap;
      if (ks < 4)       ap = emoB + aE[q] + f0;
      else if (ks < 8)  ap = cauB + aC[q] + (f0 - 512);
      else              ap = smB + aS[q];
      load_lds16(ap, ldsBase + q * 4096);
      load_lds16(bBase + q * (32 * KPAD) + f0, ldsBase + 16384 + q * 4096);
    }
    __syncthreads();

    i32x8 bv[4];
#pragma unroll
    for (int ni = 0; ni < 4; ++ni) {
      const char* base = Bs + (wn + ni * 16 + lrow) * 128;
      i32x4 lo = *(const i32x4*)(base + ca0);
      i32x4 hi = *(const i32x4*)(base + ca1);
      bv[ni] = __builtin_shufflevector(lo, hi, 0, 1, 2, 3, 4, 5, 6, 7);
    }
#pragma unroll
    for (int mi = 0; mi < 4; ++mi) {
      const char* base = As + (wm + mi * 16 + lrow) * 128;
      i32x4 lo = *(const i32x4*)(base + ca0);
      i32x4 hi = *(const i32x4*)(base + ca1);
      i32x8 av = __builtin_shufflevector(lo, hi, 0, 1, 2, 3, 4, 5, 6, 7);
#pragma unroll
      for (int ni = 0; ni < 4; ++ni)
        acc[mi][ni] = __builtin_amdgcn_mfma_scale_f32_16x16x128_f8f6f4(
            av, bv[ni], acc[mi][ni], 0, 0, 0, 0x7f7f7f7f, 0, 0x7f7f7f7f);
    }
    __syncthreads();
  }

  // epilogue: un-scale W1 (x1/64), +b1, relu, dot W2, reduce over g-cols
  float rs[4][4];
#pragma unroll
  for (int mi = 0; mi < 4; ++mi)
#pragma unroll
    for (int r2 = 0; r2 < 4; ++r2) rs[mi][r2] = 0.f;

#pragma unroll
  for (int ni = 0; ni < 4; ++ni) {
    int g = gbase + wn + ni * 16 + lrow;
    float w2v = w2p[g];
    float b1v = b1p[g];
#pragma unroll
    for (int mi = 0; mi < 4; ++mi)
#pragma unroll
      for (int r2 = 0; r2 < 4; ++r2) {
        float hv = acc[mi][ni][r2] * W1INV + b1v;
        hv = fmaxf(hv, 0.f);
        rs[mi][r2] += hv * w2v;
      }
  }
#pragma unroll
  for (int mi = 0; mi < 4; ++mi)
#pragma unroll
    for (int r2 = 0; r2 < 4; ++r2) {
      float v2 = rs[mi][r2];
      v2 += __shfl_xor(v2, 1, 16);
      v2 += __shfl_xor(v2, 2, 16);
      v2 += __shfl_xor(v2, 4, 16);
      v2 += __shfl_xor(v2, 8, 16);
      if (lrow == 0)
        predAcc[w & 1][wm + mi * 16 + q2 * 4 + r2] += v2;
    }
  __syncthreads();
  if (tid < 128) {
    int r = blockIdx.x * 128 + tid;
    atomicAdd(&pred[r], predAcc[0][tid] + predAcc[1][tid]);
  }
}

extern "C" void kernel_launch(void* const* d_in, const int* in_sizes, int n_in,
                              void* d_out, int out_size, void* d_ws, size_t ws_size,
                              hipStream_t stream) {
  const float* h_emo = (const float*)d_in[0];
  const float* h_cau = (const float*)d_in[1];
  const float* pos_emb = (const float*)d_in[2];
  const float* W1 = (const float*)d_in[3];
  const float* b1 = (const float*)d_in[4];
  const float* W2 = (const float*)d_in[5];
  const float* b2 = (const float*)d_in[6];

  char* ws = (char*)d_ws;
  char* W1p = ws + WS_W1P;
  char* emoB = ws + WS_EMOB;
  char* cauB = ws + WS_CAUB;
  char* smB = ws + WS_SMB;
  float* b1p = (float*)(ws + WS_B1P);
  float* w2p = (float*)(ws + WS_W2P);
  int* tab_i = (int*)(ws + WS_TABI);
  int* tab_j = (int*)(ws + WS_TABJ);
  int* tab_r = (int*)(ws + WS_TABR);

  float* pred = (float*)d_out;
  float* out_pos = (float*)d_out + MTOT;

  setup_all<<<3379, 256, 0, stream>>>(h_emo, h_cau, pos_emb, W1, b1, W2, b2,
                                      W1p, emoB, cauB, smB, b1p, w2p,
                                      tab_i, tab_j, tab_r, pred, out_pos);
  pair_gemm<<<dim3(263, 9), 256, 0, stream>>>(emoB, cauB, smB, W1p, b1p, w2p,
                                              tab_i, tab_j, tab_r, pred);
}